// Round 1
// baseline (23432.236 us; speedup 1.0000x reference)
//
#include <hip/hip_runtime.h>
#include <math.h>

#define HD   512
#define BB   256
#define TT   200
#define DIN  64
#define DOUT 64
#define NCLS 10
#define LIPC 0.909f

__device__ __forceinline__ float lipswish(float x) {
    return LIPC * x / (1.0f + expf(-x));
}

// ---------------------------------------------------------------------------
// Kernel 1: gs[t, :] = (lipswish(tt @ Wg1 + bg1) @ Wg2 + bg2) * sqrt(dt_t)
//           tt = times[t] * W_noise + b_noise
// grid = T-1 blocks, 512 threads
// ---------------------------------------------------------------------------
__global__ __launch_bounds__(512) void g_kernel(
    const float* __restrict__ times, const float* __restrict__ W_noise,
    const float* __restrict__ b_noise, const float* __restrict__ Wg1,
    const float* __restrict__ bg1, const float* __restrict__ Wg2,
    const float* __restrict__ bg2, float* __restrict__ gs)
{
    int t = blockIdx.x;          // 0..T-2
    int j = threadIdx.x;         // 0..511
    __shared__ float tt[HD];
    __shared__ float h[HD];
    float tv = times[t];
    tt[j] = tv * W_noise[j] + b_noise[j];
    __syncthreads();
    float acc = bg1[j];
#pragma unroll 8
    for (int k = 0; k < HD; ++k) acc = fmaf(tt[k], Wg1[k * HD + j], acc);
    h[j] = lipswish(acc);
    __syncthreads();
    float acc2 = bg2[j];
#pragma unroll 8
    for (int k = 0; k < HD; ++k) acc2 = fmaf(h[k], Wg2[k * HD + j], acc2);
    float dt = times[t + 1] - times[t];
    gs[t * HD + j] = acc2 * sqrtf(dt);
}

// ---------------------------------------------------------------------------
// Kernel 2: the SDE scan, batch-parallel (one workgroup = one batch row),
// zero inter-workgroup communication. Fuses: xw matvec, emb/f1/f2/out chain,
// Euler update with precomputed gs * noise, per-step decode (W_dec), and the
// final classifier (W_cls).
// grid = B blocks, 512 threads
// ---------------------------------------------------------------------------
__global__ __launch_bounds__(512) void scan_kernel(
    const float* __restrict__ coeffs,   // (B, T-1, 4*DIN)
    const float* __restrict__ times,    // (T)
    const float* __restrict__ noise,    // (T-1, B, H)
    const float* __restrict__ W_X,  const float* __restrict__ b_X,
    const float* __restrict__ W_emb, const float* __restrict__ b_emb,
    const float* __restrict__ Wf1,  const float* __restrict__ bf1,
    const float* __restrict__ Wf2,  const float* __restrict__ bf2,
    const float* __restrict__ W_out, const float* __restrict__ b_out,
    const float* __restrict__ W_init, const float* __restrict__ b_init,
    const float* __restrict__ W_dec, const float* __restrict__ b_dec,
    const float* __restrict__ W_cls, const float* __restrict__ b_cls,
    const int* __restrict__ mask,       // (B, T)
    const float* __restrict__ gs,       // (T-1, H) pre-scaled by sqrt(dt)
    float* __restrict__ out)            // predicted (B,T,DOUT) ++ logits (B,NCLS)
{
    const int b = blockIdx.x;
    const int j = threadIdx.x;          // 0..511

    __shared__ float cat[2 * HD];       // [y (H) | xw (H)]
    __shared__ float buf1[HD];
    __shared__ float buf2[HD];
    __shared__ float red[HD];
    __shared__ float zfin[HD];
    __shared__ float tl[TT];
    __shared__ int   last_idx_s;

    if (j < TT) tl[j] = times[j];

    // ---- per-row length from mask -> last_idx ----
    {
        int m = 0;
        for (int t = j; t < TT; t += 512) m += mask[b * TT + t];
        red[j] = (float)m;
        __syncthreads();
        for (int s = 256; s > 0; s >>= 1) {
            if (j < s) red[j] += red[j + s];
            __syncthreads();
        }
        if (j == 0) last_idx_s = (int)red[0] - 1;
        __syncthreads();
    }
    const int last_idx = last_idx_s;

    // ---- y0 = a0 @ W_init + b_init ----
    if (j < DIN) buf1[j] = coeffs[(size_t)b * (TT - 1) * (4 * DIN) + j];
    __syncthreads();
    {
        float y = b_init[j];
#pragma unroll 8
        for (int k = 0; k < DIN; ++k) y = fmaf(buf1[k], W_init[k * HD + j], y);
        cat[j] = y;
        if (last_idx == 0) zfin[j] = y;
    }
    __syncthreads();

    // ---- decode index 0: out[b,0,:] = y0 @ W_dec + b_dec ----
    {
        int c = j & 63, seg = j >> 6;           // 8 segments x 64 k
        float p = 0.f;
#pragma unroll 8
        for (int k = seg * 64; k < seg * 64 + 64; ++k)
            p = fmaf(cat[k], W_dec[k * DOUT + c], p);
        red[j] = p;
        __syncthreads();
        if (j < DOUT) {
            float s = b_dec[j];
#pragma unroll
            for (int s8 = 0; s8 < 8; ++s8) s += red[s8 * 64 + j];
            out[((size_t)b * TT + 0) * DOUT + j] = s;
        }
    }
    __syncthreads();

    // ---- main scan: t = 0..T-2, y_{t+1} = y_t + drift*dt + gs[t]*noise[t,b] ----
    for (int t = 0; t < TT - 1; ++t) {
        // a_t -> red[0:64]
        if (j < DIN) red[j] = coeffs[((size_t)b * (TT - 1) + t) * (4 * DIN) + j];
        __syncthreads();
        // xw = a_t @ W_X + b_X
        {
            float xw = b_X[j];
#pragma unroll 8
            for (int k = 0; k < DIN; ++k) xw = fmaf(red[k], W_X[k * HD + j], xw);
            cat[HD + j] = xw;
        }
        __syncthreads();
        // z1 = [y, xw] @ W_emb + b_emb
        {
            float z1 = b_emb[j];
#pragma unroll 8
            for (int k = 0; k < 2 * HD; ++k) z1 = fmaf(cat[k], W_emb[k * HD + j], z1);
            buf1[j] = z1;
        }
        __syncthreads();
        // z2 = lipswish(z1 @ Wf1 + bf1)
        {
            float a1 = bf1[j];
#pragma unroll 8
            for (int k = 0; k < HD; ++k) a1 = fmaf(buf1[k], Wf1[k * HD + j], a1);
            buf2[j] = lipswish(a1);
        }
        __syncthreads();
        // z3 = z2 @ Wf2 + bf2
        {
            float a2 = bf2[j];
#pragma unroll 8
            for (int k = 0; k < HD; ++k) a2 = fmaf(buf2[k], Wf2[k * HD + j], a2);
            buf1[j] = a2;
        }
        __syncthreads();
        // drift = z3 @ W_out + b_out;  Euler update
        {
            float dr = b_out[j];
#pragma unroll 8
            for (int k = 0; k < HD; ++k) dr = fmaf(buf1[k], W_out[k * HD + j], dr);
            float dtv = tl[t + 1] - tl[t];
            float yn = cat[j] + dr * dtv
                     + gs[(size_t)t * HD + j] * noise[((size_t)t * BB + b) * HD + j];
            cat[j] = yn;                         // no reader of cat in this window
            if (t + 1 == last_idx) zfin[j] = yn;
        }
        __syncthreads();
        // decode: out[b, t+1, :] = y_{t+1} @ W_dec + b_dec
        {
            int c = j & 63, seg = j >> 6;
            float p = 0.f;
#pragma unroll 8
            for (int k = seg * 64; k < seg * 64 + 64; ++k)
                p = fmaf(cat[k], W_dec[k * DOUT + c], p);
            red[j] = p;
            __syncthreads();
            if (j < DOUT) {
                float s = b_dec[j];
#pragma unroll
                for (int s8 = 0; s8 < 8; ++s8) s += red[s8 * 64 + j];
                out[((size_t)b * TT + (t + 1)) * DOUT + j] = s;
            }
        }
        __syncthreads();   // red reused at top of next iteration
    }

    // ---- logits = z_final @ W_cls + b_cls ----
    {
        int c = j & 15, seg = j >> 4;            // 32 segments x 16 k
        float p = 0.f;
        if (c < NCLS) {
#pragma unroll
            for (int k = seg * 16; k < seg * 16 + 16; ++k)
                p = fmaf(zfin[k], W_cls[k * NCLS + c], p);
        }
        red[j] = p;
        __syncthreads();
        if (j < NCLS) {
            float s = b_cls[j];
#pragma unroll
            for (int sg = 0; sg < 32; ++sg) s += red[sg * 16 + j];
            out[(size_t)BB * TT * DOUT + b * NCLS + j] = s;
        }
    }
}

extern "C" void kernel_launch(void* const* d_in, const int* in_sizes, int n_in,
                              void* d_out, int out_size, void* d_ws, size_t ws_size,
                              hipStream_t stream)
{
    const float* coeffs  = (const float*)d_in[0];
    const float* times   = (const float*)d_in[1];
    const float* noise   = (const float*)d_in[2];
    const float* W_X     = (const float*)d_in[3];
    const float* b_X     = (const float*)d_in[4];
    const float* W_emb   = (const float*)d_in[5];
    const float* b_emb   = (const float*)d_in[6];
    const float* Wf1     = (const float*)d_in[7];
    const float* bf1     = (const float*)d_in[8];
    const float* Wf2     = (const float*)d_in[9];
    const float* bf2     = (const float*)d_in[10];
    const float* W_out   = (const float*)d_in[11];
    const float* b_out   = (const float*)d_in[12];
    const float* W_noise = (const float*)d_in[13];
    const float* b_noise = (const float*)d_in[14];
    const float* Wg1     = (const float*)d_in[15];
    const float* bg1     = (const float*)d_in[16];
    const float* Wg2     = (const float*)d_in[17];
    const float* bg2     = (const float*)d_in[18];
    const float* W_init  = (const float*)d_in[19];
    const float* b_init  = (const float*)d_in[20];
    const float* W_dec   = (const float*)d_in[21];
    const float* b_dec   = (const float*)d_in[22];
    const float* W_cls   = (const float*)d_in[23];
    const float* b_cls   = (const float*)d_in[24];
    const int*   mask    = (const int*)d_in[25];

    float* gs  = (float*)d_ws;          // (T-1, H) = 407,552 B
    float* out = (float*)d_out;

    g_kernel<<<dim3(TT - 1), dim3(HD), 0, stream>>>(
        times, W_noise, b_noise, Wg1, bg1, Wg2, bg2, gs);

    scan_kernel<<<dim3(BB), dim3(HD), 0, stream>>>(
        coeffs, times, noise, W_X, b_X, W_emb, b_emb, Wf1, bf1, Wf2, bf2,
        W_out, b_out, W_init, b_init, W_dec, b_dec, W_cls, b_cls, mask, gs, out);
}

// Round 2
// 11128.201 us; speedup vs baseline: 2.1057x; 2.1057x over previous
//
#include <hip/hip_runtime.h>
#include <math.h>

#define HD   512
#define BB   256
#define TT   200
#define DIN  64
#define DOUT 64
#define NCLS 10
#define LIPC 0.909f

__device__ __forceinline__ float lipswish(float x) {
    return LIPC * x / (1.0f + expf(-x));
}

// ---------------------------------------------------------------------------
// Partial matvec, 512 threads: 4 k-groups (g=j>>7) x 128 float4-columns
// (c=j&127). Each thread accumulates 4 outputs (cols 4c..4c+3) over its
// group's K/4 k's with float4 weight loads (coalesced 1KB/inst/wave).
// part[g*HD + 4c+i] holds the partial; caller reduces over g.
// ---------------------------------------------------------------------------
template<int K>
__device__ __forceinline__ void mv_part(const float* __restrict__ W,
                                        const float* src, float* part, int j)
{
    const int g = j >> 7, c = j & 127;
    const int kpg = K >> 2;
    const int k0 = g * kpg;
    const float4* __restrict__ W4 = (const float4*)W;
    float4 acc; acc.x = acc.y = acc.z = acc.w = 0.f;
#pragma unroll 2
    for (int k = k0; k < k0 + kpg; k += 4) {
        float4 a  = *(const float4*)(src + k);          // LDS broadcast
        float4 w0 = W4[(size_t)(k + 0) * 128 + c];
        float4 w1 = W4[(size_t)(k + 1) * 128 + c];
        float4 w2 = W4[(size_t)(k + 2) * 128 + c];
        float4 w3 = W4[(size_t)(k + 3) * 128 + c];
        acc.x = fmaf(a.x, w0.x, acc.x); acc.y = fmaf(a.x, w0.y, acc.y);
        acc.z = fmaf(a.x, w0.z, acc.z); acc.w = fmaf(a.x, w0.w, acc.w);
        acc.x = fmaf(a.y, w1.x, acc.x); acc.y = fmaf(a.y, w1.y, acc.y);
        acc.z = fmaf(a.y, w1.z, acc.z); acc.w = fmaf(a.y, w1.w, acc.w);
        acc.x = fmaf(a.z, w2.x, acc.x); acc.y = fmaf(a.z, w2.y, acc.y);
        acc.z = fmaf(a.z, w2.z, acc.z); acc.w = fmaf(a.z, w2.w, acc.w);
        acc.x = fmaf(a.w, w3.x, acc.x); acc.y = fmaf(a.w, w3.y, acc.y);
        acc.z = fmaf(a.w, w3.z, acc.z); acc.w = fmaf(a.w, w3.w, acc.w);
    }
    *(float4*)(part + g * HD + 4 * c) = acc;
}

#define MV_REDUCE(bias, j) ((bias)[j] + part[j] + part[HD + (j)] + part[2 * HD + (j)] + part[3 * HD + (j)])

// ---------------------------------------------------------------------------
// Kernel 1: gs[t,:] = (lipswish(tt @ Wg1 + bg1) @ Wg2 + bg2) * sqrt(dt)
// ---------------------------------------------------------------------------
__global__ __launch_bounds__(512) void g_kernel(
    const float* __restrict__ times, const float* __restrict__ W_noise,
    const float* __restrict__ b_noise, const float* __restrict__ Wg1,
    const float* __restrict__ bg1, const float* __restrict__ Wg2,
    const float* __restrict__ bg2, float* __restrict__ gs)
{
    int t = blockIdx.x;
    int j = threadIdx.x;
    __shared__ float tt[HD];
    __shared__ float h[HD];
    __shared__ float part[4 * HD];
    float tv = times[t];
    tt[j] = tv * W_noise[j] + b_noise[j];
    __syncthreads();
    mv_part<HD>(Wg1, tt, part, j);
    __syncthreads();
    h[j] = lipswish(MV_REDUCE(bg1, j));
    __syncthreads();
    mv_part<HD>(Wg2, h, part, j);
    __syncthreads();
    float dt = times[t + 1] - times[t];
    gs[t * HD + j] = MV_REDUCE(bg2, j) * sqrtf(dt);
}

// ---------------------------------------------------------------------------
// Kernel 2: batch-parallel SDE scan, one workgroup per batch row.
// ---------------------------------------------------------------------------
__global__ __launch_bounds__(512) void scan_kernel(
    const float* __restrict__ coeffs,
    const float* __restrict__ times,
    const float* __restrict__ noise,
    const float* __restrict__ W_X,  const float* __restrict__ b_X,
    const float* __restrict__ W_emb, const float* __restrict__ b_emb,
    const float* __restrict__ Wf1,  const float* __restrict__ bf1,
    const float* __restrict__ Wf2,  const float* __restrict__ bf2,
    const float* __restrict__ W_out, const float* __restrict__ b_out,
    const float* __restrict__ W_init, const float* __restrict__ b_init,
    const float* __restrict__ W_dec, const float* __restrict__ b_dec,
    const float* __restrict__ W_cls, const float* __restrict__ b_cls,
    const int* __restrict__ mask,
    const float* __restrict__ gs,
    float* __restrict__ out)
{
    const int b = blockIdx.x;
    const int j = threadIdx.x;

    __shared__ float cat[2 * HD];      // [y | xw]
    __shared__ float actA[HD];
    __shared__ float actB[HD];
    __shared__ float part[4 * HD];
    __shared__ float avec[DIN];
    __shared__ float zfin[HD];
    __shared__ float tl[TT];
    __shared__ int   last_idx_s;

    if (j < TT) tl[j] = times[j];

    // ---- per-row length from mask ----
    {
        int m = 0;
        for (int t = j; t < TT; t += 512) m += mask[b * TT + t];
        part[j] = (float)m;
        __syncthreads();
        for (int s = 256; s > 0; s >>= 1) {
            if (j < s) part[j] += part[j + s];
            __syncthreads();
        }
        if (j == 0) last_idx_s = (int)part[0] - 1;
        __syncthreads();
    }
    const int last_idx = last_idx_s;

    // ---- y0 = a0 @ W_init + b_init ----
    if (j < DIN / 4)
        ((float4*)avec)[j] = ((const float4*)(coeffs + (size_t)b * (TT - 1) * 4 * DIN))[j];
    __syncthreads();
    mv_part<DIN>(W_init, avec, part, j);
    __syncthreads();
    {
        float y = MV_REDUCE(b_init, j);
        cat[j] = y;
        if (last_idx == 0) zfin[j] = y;
    }
    __syncthreads();

    // ---- decode y0 -> out[b,0,:] ----
    {
        const int c4 = j & 15, g = j >> 4;     // 32 k-groups x 16 float4 cols
        const float4* __restrict__ Wd4 = (const float4*)W_dec;
        float4 acc; acc.x = acc.y = acc.z = acc.w = 0.f;
#pragma unroll
        for (int k = g * 16; k < g * 16 + 16; ++k) {
            float a = cat[k];
            float4 w = Wd4[k * 16 + c4];
            acc.x = fmaf(a, w.x, acc.x); acc.y = fmaf(a, w.y, acc.y);
            acc.z = fmaf(a, w.z, acc.z); acc.w = fmaf(a, w.w, acc.w);
        }
        *(float4*)(part + g * 64 + 4 * c4) = acc;
        __syncthreads();
        if (j < DOUT) {
            float s = b_dec[j];
#pragma unroll
            for (int g2 = 0; g2 < 32; ++g2) s += part[g2 * 64 + j];
            out[((size_t)b * TT + 0) * DOUT + j] = s;
        }
        __syncthreads();
    }

    // ---- main scan ----
    for (int t = 0; t < TT - 1; ++t) {
        // a_t
        if (j < DIN / 4)
            ((float4*)avec)[j] =
                ((const float4*)(coeffs + ((size_t)b * (TT - 1) + t) * 4 * DIN))[j];
        __syncthreads();
        // xw = a_t @ W_X + b_X
        mv_part<DIN>(W_X, avec, part, j);
        __syncthreads();
        cat[HD + j] = MV_REDUCE(b_X, j);
        __syncthreads();
        // z1 = [y,xw] @ W_emb + b_emb
        mv_part<2 * HD>(W_emb, cat, part, j);
        __syncthreads();
        actA[j] = MV_REDUCE(b_emb, j);
        __syncthreads();
        // z2 = lipswish(z1 @ Wf1 + bf1)
        mv_part<HD>(Wf1, actA, part, j);
        __syncthreads();
        actB[j] = lipswish(MV_REDUCE(bf1, j));
        __syncthreads();
        // z3 = z2 @ Wf2 + bf2
        mv_part<HD>(Wf2, actB, part, j);
        __syncthreads();
        actA[j] = MV_REDUCE(bf2, j);
        __syncthreads();
        // drift = z3 @ W_out + b_out; Euler update
        mv_part<HD>(W_out, actA, part, j);
        __syncthreads();
        {
            float dr = MV_REDUCE(b_out, j);
            float dtv = tl[t + 1] - tl[t];
            float yn = cat[j] + dr * dtv
                     + gs[(size_t)t * HD + j] * noise[((size_t)t * BB + b) * HD + j];
            cat[j] = yn;
            if (t + 1 == last_idx) zfin[j] = yn;
        }
        __syncthreads();
        // decode y_{t+1}
        {
            const int c4 = j & 15, g = j >> 4;
            const float4* __restrict__ Wd4 = (const float4*)W_dec;
            float4 acc; acc.x = acc.y = acc.z = acc.w = 0.f;
#pragma unroll
            for (int k = g * 16; k < g * 16 + 16; ++k) {
                float a = cat[k];
                float4 w = Wd4[k * 16 + c4];
                acc.x = fmaf(a, w.x, acc.x); acc.y = fmaf(a, w.y, acc.y);
                acc.z = fmaf(a, w.z, acc.z); acc.w = fmaf(a, w.w, acc.w);
            }
            *(float4*)(part + g * 64 + 4 * c4) = acc;
            __syncthreads();
            if (j < DOUT) {
                float s = b_dec[j];
#pragma unroll
                for (int g2 = 0; g2 < 32; ++g2) s += part[g2 * 64 + j];
                out[((size_t)b * TT + (t + 1)) * DOUT + j] = s;
            }
            __syncthreads();
        }
    }

    // ---- logits = z_final @ W_cls + b_cls ----
    {
        int c = j & 15, seg = j >> 4;
        float p = 0.f;
        if (c < NCLS) {
#pragma unroll
            for (int k = seg * 16; k < seg * 16 + 16; ++k)
                p = fmaf(zfin[k], W_cls[k * NCLS + c], p);
        }
        part[j] = p;
        __syncthreads();
        if (j < NCLS) {
            float s = b_cls[j];
#pragma unroll
            for (int sg = 0; sg < 32; ++sg) s += part[sg * 16 + j];
            out[(size_t)BB * TT * DOUT + b * NCLS + j] = s;
        }
    }
}

extern "C" void kernel_launch(void* const* d_in, const int* in_sizes, int n_in,
                              void* d_out, int out_size, void* d_ws, size_t ws_size,
                              hipStream_t stream)
{
    const float* coeffs  = (const float*)d_in[0];
    const float* times   = (const float*)d_in[1];
    const float* noise   = (const float*)d_in[2];
    const float* W_X     = (const float*)d_in[3];
    const float* b_X     = (const float*)d_in[4];
    const float* W_emb   = (const float*)d_in[5];
    const float* b_emb   = (const float*)d_in[6];
    const float* Wf1     = (const float*)d_in[7];
    const float* bf1     = (const float*)d_in[8];
    const float* Wf2     = (const float*)d_in[9];
    const float* bf2     = (const float*)d_in[10];
    const float* W_out   = (const float*)d_in[11];
    const float* b_out   = (const float*)d_in[12];
    const float* W_noise = (const float*)d_in[13];
    const float* b_noise = (const float*)d_in[14];
    const float* Wg1     = (const float*)d_in[15];
    const float* bg1     = (const float*)d_in[16];
    const float* Wg2     = (const float*)d_in[17];
    const float* bg2     = (const float*)d_in[18];
    const float* W_init  = (const float*)d_in[19];
    const float* b_init  = (const float*)d_in[20];
    const float* W_dec   = (const float*)d_in[21];
    const float* b_dec   = (const float*)d_in[22];
    const float* W_cls   = (const float*)d_in[23];
    const float* b_cls   = (const float*)d_in[24];
    const int*   mask    = (const int*)d_in[25];

    float* gs  = (float*)d_ws;
    float* out = (float*)d_out;

    g_kernel<<<dim3(TT - 1), dim3(HD), 0, stream>>>(
        times, W_noise, b_noise, Wg1, bg1, Wg2, bg2, gs);

    scan_kernel<<<dim3(BB), dim3(HD), 0, stream>>>(
        coeffs, times, noise, W_X, b_X, W_emb, b_emb, Wf1, bf1, Wf2, bf2,
        W_out, b_out, W_init, b_init, W_dec, b_dec, W_cls, b_cls, mask, gs, out);
}

// Round 3
// 6590.931 us; speedup vs baseline: 3.5552x; 1.6884x over previous
//
#include <hip/hip_runtime.h>
#include <hip/hip_fp16.h>
#include <math.h>

#define HD   512
#define BB   256
#define TT   200
#define DIN  64
#define DOUT 64
#define NCLS 10
#define LIPC 0.909f

// fp16 weight pack layout in d_ws (halves), after gs (= (TT-1)*HD floats = 407552 B)
#define GS_BYTES   407552
#define OFF_WX     0
#define OFF_WEMB   32768
#define OFF_WF1    557056
#define OFF_WF2    819200
#define OFF_WOUT   1081344
#define OFF_WDEC   1343488
#define NHALVES    1376256

__device__ __forceinline__ float lipswish(float x) {
    return LIPC * x / (1.0f + expf(-x));
}

__device__ __forceinline__ void fma8h(float a, uint4 raw, float* acc) {
    __half2 h; float2 f;
    h = *(__half2*)&raw.x; f = __half22float2(h);
    acc[0] = fmaf(a, f.x, acc[0]); acc[1] = fmaf(a, f.y, acc[1]);
    h = *(__half2*)&raw.y; f = __half22float2(h);
    acc[2] = fmaf(a, f.x, acc[2]); acc[3] = fmaf(a, f.y, acc[3]);
    h = *(__half2*)&raw.z; f = __half22float2(h);
    acc[4] = fmaf(a, f.x, acc[4]); acc[5] = fmaf(a, f.y, acc[5]);
    h = *(__half2*)&raw.w; f = __half22float2(h);
    acc[6] = fmaf(a, f.x, acc[6]); acc[7] = fmaf(a, f.y, acc[7]);
}

// ---------------------------------------------------------------------------
// fp32 -> fp16 weight conversion. grid = 2688 blocks x 512.
// Segment boundaries (blocks): 64, 1088, 1600, 2112, 2624, 2688.
// ---------------------------------------------------------------------------
__global__ __launch_bounds__(512) void cvt_kernel(
    const float* __restrict__ W_X,  const float* __restrict__ W_emb,
    const float* __restrict__ Wf1,  const float* __restrict__ Wf2,
    const float* __restrict__ W_out, const float* __restrict__ W_dec,
    __half* __restrict__ dst)
{
    int bid = blockIdx.x;
    size_t idx = ((size_t)bid << 9) + threadIdx.x;
    const float* src; size_t off;
    if      (bid < 64)   { src = W_X;   off = OFF_WX;   }
    else if (bid < 1088) { src = W_emb; off = OFF_WEMB; }
    else if (bid < 1600) { src = Wf1;   off = OFF_WF1;  }
    else if (bid < 2112) { src = Wf2;   off = OFF_WF2;  }
    else if (bid < 2624) { src = W_out; off = OFF_WOUT; }
    else                 { src = W_dec; off = OFF_WDEC; }
    dst[idx] = __float2half(src[idx - off]);
}

// ---------------------------------------------------------------------------
// fp32 partial matvec (used only for one-time W_init and g_kernel):
// 4 k-groups x 128 float4-cols, partials in part[4*HD].
// ---------------------------------------------------------------------------
template<int K>
__device__ __forceinline__ void mv_part(const float* __restrict__ W,
                                        const float* src, float* part, int j)
{
    const int g = j >> 7, c = j & 127;
    const int kpg = K >> 2;
    const int k0 = g * kpg;
    const float4* __restrict__ W4 = (const float4*)W;
    float4 acc; acc.x = acc.y = acc.z = acc.w = 0.f;
#pragma unroll 2
    for (int k = k0; k < k0 + kpg; k += 4) {
        float4 a  = *(const float4*)(src + k);
        float4 w0 = W4[(size_t)(k + 0) * 128 + c];
        float4 w1 = W4[(size_t)(k + 1) * 128 + c];
        float4 w2 = W4[(size_t)(k + 2) * 128 + c];
        float4 w3 = W4[(size_t)(k + 3) * 128 + c];
        acc.x = fmaf(a.x, w0.x, acc.x); acc.y = fmaf(a.x, w0.y, acc.y);
        acc.z = fmaf(a.x, w0.z, acc.z); acc.w = fmaf(a.x, w0.w, acc.w);
        acc.x = fmaf(a.y, w1.x, acc.x); acc.y = fmaf(a.y, w1.y, acc.y);
        acc.z = fmaf(a.y, w1.z, acc.z); acc.w = fmaf(a.y, w1.w, acc.w);
        acc.x = fmaf(a.z, w2.x, acc.x); acc.y = fmaf(a.z, w2.y, acc.y);
        acc.z = fmaf(a.z, w2.z, acc.z); acc.w = fmaf(a.z, w2.w, acc.w);
        acc.x = fmaf(a.w, w3.x, acc.x); acc.y = fmaf(a.w, w3.y, acc.y);
        acc.z = fmaf(a.w, w3.z, acc.z); acc.w = fmaf(a.w, w3.w, acc.w);
    }
    *(float4*)(part + g * HD + 4 * c) = acc;
}

#define MV_REDUCE4(bias, j) ((bias)[j] + part[j] + part[HD + (j)] + part[2 * HD + (j)] + part[3 * HD + (j)])
#define MV_REDUCE8(bias, j) ((bias)[j] + part[j] + part[HD + (j)] + part[2 * HD + (j)] + part[3 * HD + (j)] \
                           + part[4 * HD + (j)] + part[5 * HD + (j)] + part[6 * HD + (j)] + part[7 * HD + (j)])

// ---------------------------------------------------------------------------
// fp16 partial matvec, NC=512 outputs: 8 k-groups (g=j>>6) x 64 col-octets.
// Each thread: 8 output cols, one uint4 (8 halves) load per k.
// ---------------------------------------------------------------------------
template<int K>
__device__ __forceinline__ void mv_part_h(const __half* __restrict__ W,
                                          const float* src, float* part, int j)
{
    const int g = j >> 6, c8 = (j & 63) << 3;
    const int kpg = K >> 3;
    const int k0 = g * kpg;
    float acc[8];
#pragma unroll
    for (int i = 0; i < 8; ++i) acc[i] = 0.f;
#pragma unroll 8
    for (int k = k0; k < k0 + kpg; ++k) {
        float a = src[k];
        uint4 raw = *(const uint4*)(W + ((size_t)k << 9) + c8);
        fma8h(a, raw, acc);
    }
    *(float4*)(part + g * HD + c8)     = make_float4(acc[0], acc[1], acc[2], acc[3]);
    *(float4*)(part + g * HD + c8 + 4) = make_float4(acc[4], acc[5], acc[6], acc[7]);
}

// ---------------------------------------------------------------------------
// fp16 decode (512 -> 64) + store: 64 k-groups x 8 col-octets.
// part: 4096 floats scratch; scr: 512 floats scratch.
// ---------------------------------------------------------------------------
__device__ __forceinline__ void decode_store_h(const __half* __restrict__ Wd,
    const float* __restrict__ b_dec, const float* y, float* part, float* scr,
    int j, float* __restrict__ outp)
{
    const int g = j >> 3, c8 = (j & 7) << 3;
    const int k0 = g << 3;
    float acc[8];
#pragma unroll
    for (int i = 0; i < 8; ++i) acc[i] = 0.f;
#pragma unroll
    for (int k = k0; k < k0 + 8; ++k) {
        float a = y[k];
        uint4 raw = *(const uint4*)(Wd + ((size_t)k << 6) + c8);
        fma8h(a, raw, acc);
    }
    *(float4*)(part + (g << 6) + c8)     = make_float4(acc[0], acc[1], acc[2], acc[3]);
    *(float4*)(part + (g << 6) + c8 + 4) = make_float4(acc[4], acc[5], acc[6], acc[7]);
    __syncthreads();
    {
        int o = j >> 6, col = j & 63;
        float s = 0.f;
#pragma unroll
        for (int i = 0; i < 8; ++i) s += part[((o << 3) + i) * 64 + col];
        scr[(o << 6) + col] = s;
    }
    __syncthreads();
    if (j < DOUT) {
        float s = b_dec[j];
#pragma unroll
        for (int i = 0; i < 8; ++i) s += scr[(i << 6) + j];
        outp[j] = s;
    }
    __syncthreads();
}

// ---------------------------------------------------------------------------
// Kernel 1: gs[t,:] = (lipswish(tt @ Wg1 + bg1) @ Wg2 + bg2) * sqrt(dt)
// ---------------------------------------------------------------------------
__global__ __launch_bounds__(512) void g_kernel(
    const float* __restrict__ times, const float* __restrict__ W_noise,
    const float* __restrict__ b_noise, const float* __restrict__ Wg1,
    const float* __restrict__ bg1, const float* __restrict__ Wg2,
    const float* __restrict__ bg2, float* __restrict__ gs)
{
    int t = blockIdx.x;
    int j = threadIdx.x;
    __shared__ float tt[HD];
    __shared__ float h[HD];
    __shared__ float part[4 * HD];
    float tv = times[t];
    tt[j] = tv * W_noise[j] + b_noise[j];
    __syncthreads();
    mv_part<HD>(Wg1, tt, part, j);
    __syncthreads();
    h[j] = lipswish(MV_REDUCE4(bg1, j));
    __syncthreads();
    mv_part<HD>(Wg2, h, part, j);
    __syncthreads();
    float dt = times[t + 1] - times[t];
    gs[t * HD + j] = MV_REDUCE4(bg2, j) * sqrtf(dt);
}

// ---------------------------------------------------------------------------
// Kernel 2: batch-parallel SDE scan, fp16 streamed weights.
// ---------------------------------------------------------------------------
__global__ __launch_bounds__(512) void scan_kernel(
    const float* __restrict__ coeffs,
    const float* __restrict__ times,
    const float* __restrict__ noise,
    const float* __restrict__ b_X,
    const float* __restrict__ b_emb,
    const float* __restrict__ bf1,
    const float* __restrict__ bf2,
    const float* __restrict__ b_out,
    const float* __restrict__ W_init, const float* __restrict__ b_init,
    const float* __restrict__ b_dec,
    const float* __restrict__ W_cls, const float* __restrict__ b_cls,
    const int* __restrict__ mask,
    const float* __restrict__ gs,
    const __half* __restrict__ Wh,      // packed fp16 weights
    float* __restrict__ out)
{
    const int b = blockIdx.x;
    const int j = threadIdx.x;

    const __half* __restrict__ W_X_h   = Wh + OFF_WX;
    const __half* __restrict__ W_emb_h = Wh + OFF_WEMB;
    const __half* __restrict__ Wf1_h   = Wh + OFF_WF1;
    const __half* __restrict__ Wf2_h   = Wh + OFF_WF2;
    const __half* __restrict__ W_out_h = Wh + OFF_WOUT;
    const __half* __restrict__ W_dec_h = Wh + OFF_WDEC;

    __shared__ float cat[2 * HD];      // [y | xw]
    __shared__ float actA[HD];
    __shared__ float actB[HD];
    __shared__ float part[8 * HD];     // 16 KB partials
    __shared__ float avec[DIN];
    __shared__ float zfin[HD];
    __shared__ float tl[TT];
    __shared__ int   last_idx_s;

    if (j < TT) tl[j] = times[j];

    // ---- per-row length from mask ----
    {
        int m = 0;
        for (int t = j; t < TT; t += 512) m += mask[b * TT + t];
        part[j] = (float)m;
        __syncthreads();
        for (int s = 256; s > 0; s >>= 1) {
            if (j < s) part[j] += part[j + s];
            __syncthreads();
        }
        if (j == 0) last_idx_s = (int)part[0] - 1;
        __syncthreads();
    }
    const int last_idx = last_idx_s;

    // ---- y0 = a0 @ W_init + b_init (fp32, one-time) ----
    if (j < DIN / 4)
        ((float4*)avec)[j] = ((const float4*)(coeffs + (size_t)b * (TT - 1) * 4 * DIN))[j];
    __syncthreads();
    mv_part<DIN>(W_init, avec, part, j);
    __syncthreads();
    {
        float y = MV_REDUCE4(b_init, j);
        cat[j] = y;
        if (last_idx == 0) zfin[j] = y;
    }
    __syncthreads();

    // ---- decode y0 ----
    decode_store_h(W_dec_h, b_dec, cat, part, actB, j,
                   out + ((size_t)b * TT + 0) * DOUT);

    // ---- main scan ----
    for (int t = 0; t < TT - 1; ++t) {
        if (j < DIN / 4)
            ((float4*)avec)[j] =
                ((const float4*)(coeffs + ((size_t)b * (TT - 1) + t) * 4 * DIN))[j];
        __syncthreads();
        // xw = a_t @ W_X + b_X
        mv_part_h<DIN>(W_X_h, avec, part, j);
        __syncthreads();
        cat[HD + j] = MV_REDUCE8(b_X, j);
        __syncthreads();
        // z1 = [y,xw] @ W_emb + b_emb
        mv_part_h<2 * HD>(W_emb_h, cat, part, j);
        __syncthreads();
        actA[j] = MV_REDUCE8(b_emb, j);
        __syncthreads();
        // z2 = lipswish(z1 @ Wf1 + bf1)
        mv_part_h<HD>(Wf1_h, actA, part, j);
        __syncthreads();
        actB[j] = lipswish(MV_REDUCE8(bf1, j));
        __syncthreads();
        // z3 = z2 @ Wf2 + bf2
        mv_part_h<HD>(Wf2_h, actB, part, j);
        __syncthreads();
        actA[j] = MV_REDUCE8(bf2, j);
        __syncthreads();
        // drift = z3 @ W_out + b_out; Euler update
        mv_part_h<HD>(W_out_h, actA, part, j);
        __syncthreads();
        {
            float dr = MV_REDUCE8(b_out, j);
            float dtv = tl[t + 1] - tl[t];
            float yn = cat[j] + dr * dtv
                     + gs[(size_t)t * HD + j] * noise[((size_t)t * BB + b) * HD + j];
            cat[j] = yn;
            if (t + 1 == last_idx) zfin[j] = yn;
        }
        __syncthreads();
        // decode y_{t+1}
        decode_store_h(W_dec_h, b_dec, cat, part, actB, j,
                       out + ((size_t)b * TT + (t + 1)) * DOUT);
    }

    // ---- logits (fp32, one-time) ----
    {
        int c = j & 15, seg = j >> 4;
        float p = 0.f;
        if (c < NCLS) {
#pragma unroll
            for (int k = seg * 16; k < seg * 16 + 16; ++k)
                p = fmaf(zfin[k], W_cls[k * NCLS + c], p);
        }
        part[j] = p;
        __syncthreads();
        if (j < NCLS) {
            float s = b_cls[j];
#pragma unroll
            for (int sg = 0; sg < 32; ++sg) s += part[sg * 16 + j];
            out[(size_t)BB * TT * DOUT + b * NCLS + j] = s;
        }
    }
}

extern "C" void kernel_launch(void* const* d_in, const int* in_sizes, int n_in,
                              void* d_out, int out_size, void* d_ws, size_t ws_size,
                              hipStream_t stream)
{
    const float* coeffs  = (const float*)d_in[0];
    const float* times   = (const float*)d_in[1];
    const float* noise   = (const float*)d_in[2];
    const float* W_X     = (const float*)d_in[3];
    const float* b_X     = (const float*)d_in[4];
    const float* W_emb   = (const float*)d_in[5];
    const float* b_emb   = (const float*)d_in[6];
    const float* Wf1     = (const float*)d_in[7];
    const float* bf1     = (const float*)d_in[8];
    const float* Wf2     = (const float*)d_in[9];
    const float* bf2     = (const float*)d_in[10];
    const float* W_out   = (const float*)d_in[11];
    const float* b_out   = (const float*)d_in[12];
    const float* W_noise = (const float*)d_in[13];
    const float* b_noise = (const float*)d_in[14];
    const float* Wg1     = (const float*)d_in[15];
    const float* bg1     = (const float*)d_in[16];
    const float* Wg2     = (const float*)d_in[17];
    const float* bg2     = (const float*)d_in[18];
    const float* W_init  = (const float*)d_in[19];
    const float* b_init  = (const float*)d_in[20];
    const float* W_dec   = (const float*)d_in[21];
    const float* b_dec   = (const float*)d_in[22];
    const float* W_cls   = (const float*)d_in[23];
    const float* b_cls   = (const float*)d_in[24];
    const int*   mask    = (const int*)d_in[25];

    float*  gs = (float*)d_ws;
    __half* Wh = (__half*)((char*)d_ws + GS_BYTES);
    float* out = (float*)d_out;

    cvt_kernel<<<dim3(NHALVES / 512), dim3(512), 0, stream>>>(
        W_X, W_emb, Wf1, Wf2, W_out, W_dec, Wh);

    g_kernel<<<dim3(TT - 1), dim3(HD), 0, stream>>>(
        times, W_noise, b_noise, Wg1, bg1, Wg2, bg2, gs);

    scan_kernel<<<dim3(BB), dim3(HD), 0, stream>>>(
        coeffs, times, noise, b_X, b_emb, bf1, bf2, b_out,
        W_init, b_init, b_dec, W_cls, b_cls, mask, gs, Wh, out);
}